// Round 1
// baseline (3007.277 us; speedup 1.0000x reference)
//
#include <hip/hip_runtime.h>
#include <hip/hip_bf16.h>

// MLA forward, round 7: attention restructured.
//  - 128 q-rows per block, 8 waves, each wave owns 16 unique rows (no cg
//    duplication of S^T), TK=32 so PV MFMAs have a full k=32 (no zero pad).
//  - K/V/wbk fragments are wave-uniform and L2-resident -> read directly from
//    global (no LDS staging, no __syncthreads at all). LDS only for in-wave
//    cross-quad redistribution (per-wave regions + compiler fences).
//  - per-wave causal early exit; exact skip of online-softmax rescale when
//    the running max did not grow (wave vote, bitwise-identical result).
// B=2 S=2048 D=2048 H=16 NOPE=128 ROPE=64 V=128 C=512
#define B_ 2
#define S_ 2048
#define H_ 16

typedef unsigned short ushort_t;
typedef unsigned int uint_t;
typedef __attribute__((ext_vector_type(8))) short bf16x8;
typedef __attribute__((ext_vector_type(4))) float f32x4;

__device__ __forceinline__ ushort_t f2bf(float f) {
    uint_t u = __float_as_uint(f);
    return (ushort_t)((u + 0x7fffu + ((u >> 16) & 1u)) >> 16);
}
__device__ __forceinline__ float bf2f(ushort_t v) {
    return __uint_as_float(((uint_t)v) << 16);
}

// ---------------------------------------------------------------------------
// f32 -> bf16 cast
// ---------------------------------------------------------------------------
__global__ __launch_bounds__(256) void cast_bf16(const float* __restrict__ src,
                                                 ushort_t* __restrict__ dst, int n)
{
    int i = (blockIdx.x * 256 + threadIdx.x) * 4;
    if (i < n) {
        float4 v = *(const float4*)(src + i);
        ushort_t pk[4] = { f2bf(v.x), f2bf(v.y), f2bf(v.z), f2bf(v.w) };
        *(uint2*)(dst + i) = *(const uint2*)pk;
    }
}

// ---------------------------------------------------------------------------
// bf16 MFMA GEMM: C[M,N] = A[M,K] @ B[N,K]^T. M,N %128==0, K%64==0.
// ---------------------------------------------------------------------------
__global__ __launch_bounds__(256, 2) void gemm_bf16(const ushort_t* __restrict__ A,
                                                    const ushort_t* __restrict__ Bm,
                                                    float* __restrict__ Cf,
                                                    ushort_t* __restrict__ Cb,
                                                    int M, int N, int K, int outBf)
{
    __shared__ __align__(16) ushort_t As[128*72];
    __shared__ __align__(16) ushort_t Bs[128*72];
    const int tid = threadIdx.x;
    const int wv = tid >> 6, lane = tid & 63, l16 = lane & 15, quad = lane >> 4;
    const int wm = wv >> 1, wn = wv & 1;
    const int m0 = blockIdx.y * 128, n0 = blockIdx.x * 128;
    const int row = tid >> 1, kh = (tid & 1) * 32;
    const ushort_t* Ag = A  + (size_t)(m0 + row) * K + kh;
    const ushort_t* Bg = Bm + (size_t)(n0 + row) * K + kh;

    f32x4 acc[16];
#pragma unroll
    for (int i = 0; i < 16; i++) acc[i] = (f32x4)(0.f);

    for (int k0 = 0; k0 < K; k0 += 64) {
        uint4 av[4], bv[4];
#pragma unroll
        for (int p = 0; p < 4; p++) {
            av[p] = *(const uint4*)(Ag + k0 + p*8);
            bv[p] = *(const uint4*)(Bg + k0 + p*8);
        }
        __syncthreads();
#pragma unroll
        for (int p = 0; p < 4; p++) {
            *(uint4*)(As + row*72 + kh + p*8) = av[p];
            *(uint4*)(Bs + row*72 + kh + p*8) = bv[p];
        }
        __syncthreads();
#pragma unroll
        for (int ks = 0; ks < 2; ks++) {
            bf16x8 af[4], bfr[4];
#pragma unroll
            for (int mt = 0; mt < 4; mt++)
                af[mt] = *(const bf16x8*)(As + (wm*64 + mt*16 + l16)*72 + ks*32 + quad*8);
#pragma unroll
            for (int nt = 0; nt < 4; nt++)
                bfr[nt] = *(const bf16x8*)(Bs + (wn*64 + nt*16 + l16)*72 + ks*32 + quad*8);
#pragma unroll
            for (int mt = 0; mt < 4; mt++)
#pragma unroll
                for (int nt = 0; nt < 4; nt++)
                    acc[mt*4+nt] = __builtin_amdgcn_mfma_f32_16x16x32_bf16(af[mt], bfr[nt], acc[mt*4+nt], 0, 0, 0);
        }
    }
#pragma unroll
    for (int mt = 0; mt < 4; mt++)
#pragma unroll
        for (int nt = 0; nt < 4; nt++)
#pragma unroll
            for (int r = 0; r < 4; r++) {
                size_t rr = m0 + wm*64 + mt*16 + quad*4 + r;
                int cc = n0 + wn*64 + nt*16 + l16;
                if (outBf) Cb[rr*N + cc] = f2bf(acc[mt*4+nt][r]);
                else       Cf[rr*N + cc] = acc[mt*4+nt][r];
            }
}

// ---------------------------------------------------------------------------
// f32 GEMM for kv-proj (kept f32 for rmsnorm accuracy).
// ---------------------------------------------------------------------------
__global__ __launch_bounds__(256) void gemm_nt(const float* __restrict__ A,
                                               const float* __restrict__ Bm,
                                               float* __restrict__ Cm,
                                               int M, int N, int K,
                                               int lda, int ldb, int ldc)
{
    __shared__ float As[16][68];
    __shared__ float Bs[16][68];
    const int tid = threadIdx.x;
    const int m0 = blockIdx.y * 64, n0 = blockIdx.x * 64;
    const int lr = tid >> 2;
    const int lc = (tid & 3) << 2;
    const int ty = tid >> 4, tx = tid & 15;
    const float* Ag = A  + (m0 + lr) * lda + lc;
    const float* Bg = Bm + (n0 + lr) * ldb + lc;

    float acc[4][4];
#pragma unroll
    for (int i = 0; i < 4; i++)
#pragma unroll
        for (int j = 0; j < 4; j++) acc[i][j] = 0.f;

    for (int k0 = 0; k0 < K; k0 += 16) {
        float4 av = *(const float4*)(Ag + k0);
        float4 bv = *(const float4*)(Bg + k0);
        __syncthreads();
        As[lc+0][lr] = av.x; As[lc+1][lr] = av.y; As[lc+2][lr] = av.z; As[lc+3][lr] = av.w;
        Bs[lc+0][lr] = bv.x; Bs[lc+1][lr] = bv.y; Bs[lc+2][lr] = bv.z; Bs[lc+3][lr] = bv.w;
        __syncthreads();
#pragma unroll
        for (int kk = 0; kk < 16; kk++) {
            float4 a = *(const float4*)&As[kk][ty*4];
            float4 b = *(const float4*)&Bs[kk][tx*4];
            acc[0][0] += a.x*b.x; acc[0][1] += a.x*b.y; acc[0][2] += a.x*b.z; acc[0][3] += a.x*b.w;
            acc[1][0] += a.y*b.x; acc[1][1] += a.y*b.y; acc[1][2] += a.y*b.z; acc[1][3] += a.y*b.w;
            acc[2][0] += a.z*b.x; acc[2][1] += a.z*b.y; acc[2][2] += a.z*b.z; acc[2][3] += a.z*b.w;
            acc[3][0] += a.w*b.x; acc[3][1] += a.w*b.y; acc[3][2] += a.w*b.z; acc[3][3] += a.w*b.w;
        }
    }
#pragma unroll
    for (int i = 0; i < 4; i++) {
        float4 r; r.x = acc[i][0]; r.y = acc[i][1]; r.z = acc[i][2]; r.w = acc[i][3];
        *(float4*)(Cm + (m0 + ty*4 + i) * ldc + n0 + tx*4) = r;
    }
}

// ---------------------------------------------------------------------------
__global__ __launch_bounds__(256) void prep_wb(const float* __restrict__ wkv_b,
                                               ushort_t* __restrict__ wbkT,
                                               ushort_t* __restrict__ wbvB)
{
    int u = blockIdx.x * 256 + threadIdx.x;
    {
        int h = u >> 16, rem = u & 65535, c = rem >> 7, d = rem & 127;
        wbkT[u] = f2bf(wkv_b[h*131072 + d*512 + c]);
    }
    {
        int h = u >> 16, rem = u & 65535;
        wbvB[u] = f2bf(wkv_b[h*131072 + 65536 + rem]);
    }
}

// ---------------------------------------------------------------------------
__global__ __launch_bounds__(256) void kv_norm_rope(const float* __restrict__ kvr,
                                                    const float* __restrict__ w,
                                                    const float* __restrict__ cosT,
                                                    const float* __restrict__ sinT,
                                                    ushort_t* __restrict__ kvnb,
                                                    ushort_t* __restrict__ kvnT,
                                                    ushort_t* __restrict__ kpeb)
{
    const int bs   = blockIdx.x * 4 + (threadIdx.x >> 6);
    const int lane = threadIdx.x & 63;
    const int s    = bs & (S_ - 1);
    const float* row = kvr + bs * 576;

    float4 v0 = *(const float4*)(row + lane*8);
    float4 v1 = *(const float4*)(row + lane*8 + 4);
    float ss = v0.x*v0.x + v0.y*v0.y + v0.z*v0.z + v0.w*v0.w
             + v1.x*v1.x + v1.y*v1.y + v1.z*v1.z + v1.w*v1.w;
#pragma unroll
    for (int off = 32; off >= 1; off >>= 1) ss += __shfl_xor(ss, off);
    const float rs = rsqrtf(ss * (1.0f/512.0f) + 1e-6f);

    float4 w0 = *(const float4*)(w + lane*8);
    float4 w1 = *(const float4*)(w + lane*8 + 4);
    float o[8];
    o[0] = v0.x*rs*w0.x; o[1] = v0.y*rs*w0.y; o[2] = v0.z*rs*w0.z; o[3] = v0.w*rs*w0.w;
    o[4] = v1.x*rs*w1.x; o[5] = v1.y*rs*w1.y; o[6] = v1.z*rs*w1.z; o[7] = v1.w*rs*w1.w;

    ushort_t pk[8];
#pragma unroll
    for (int p = 0; p < 8; p++) pk[p] = f2bf(o[p]);
    *(uint4*)(kvnb + (size_t)bs*512 + lane*8) = *(const uint4*)pk;

    const int bb = bs >> 11, t = bs & 2047;
    ushort_t* base = kvnT + ((size_t)(bb*512 + lane*8))*2048 + t;
#pragma unroll
    for (int k = 0; k < 8; k++) base[k*2048] = pk[k];

    if (lane < 32) {
        float xr = row[512 + 2*lane], xi = row[512 + 2*lane + 1];
        float c  = cosT[s*32 + lane], sn = sinT[s*32 + lane];
        ushort_t p2[2] = { f2bf(xr*c - xi*sn), f2bf(xr*sn + xi*c) };
        *(uint_t*)(kpeb + (size_t)bs*64 + 2*lane) = *(const uint_t*)p2;
    }
}

// ---------------------------------------------------------------------------
// MFMA flash attention v5: 128 q-rows/block, 8 independent waves (16 rows
// each), TK=32, K/V frags read from L2, no __syncthreads, per-wave early exit.
// ---------------------------------------------------------------------------
__global__ __launch_bounds__(512, 2) void attn_mfma(
    const ushort_t* __restrict__ qb,
    const ushort_t* __restrict__ kvnb,
    const ushort_t* __restrict__ kpeb,
    const ushort_t* __restrict__ kvnT,
    const float* __restrict__ cosT,
    const float* __restrict__ sinT,
    const ushort_t* __restrict__ wbkT,
    const ushort_t* __restrict__ wbvB,
    ushort_t* __restrict__ ovb)
{
    const int q0 = blockIdx.x * 128;
    const int h  = blockIdx.y;
    const int b  = blockIdx.z;
    const int tid  = threadIdx.x;
    const int w    = tid >> 6;
    const int lane = tid & 63;
    const int l16  = lane & 15;
    const int quad = lane >> 4;
    const int tl   = quad * 4;
    const int lb   = lane & 48;
    const float scale = 0.07216878364870323f;   // 192^-0.5

    // per-wave LDS regions only (in-wave cross-quad shuffles; fences, no barriers)
    __shared__ __align__(16) ushort_t scr_all[8 * 2176];   // 8 x (16 x 136)
    __shared__ __align__(16) ushort_t pt_all[8 * 640];     // 8 x (16 x 40)
    ushort_t* paw = scr_all + w * 2176;
    ushort_t* ptw = pt_all  + w * 640;

    const int r0    = q0 + w*16;
    const int rglob = r0 + l16;      // q-row this lane owns (as l16)

    // ===== phase A: build q_abs*scale as B-frags qf[0..15], pe -> qf[16..17]
    const ushort_t* qrow = qb + (size_t)(b*S_ + rglob)*3072 + h*192;
    bf16x8 qa[4], qf[18];
#pragma unroll
    for (int ks = 0; ks < 4; ks++)
        qa[ks] = *(const bf16x8*)(qrow + ks*32 + quad*8);

    const ushort_t* wbk_h = wbkT + h*65536;
#pragma unroll
    for (int qq = 0; qq < 4; qq++) {
        f32x4 ab[8];
#pragma unroll
        for (int n = 0; n < 8; n++) ab[n] = (f32x4)(0.f);
#pragma unroll
        for (int n = 0; n < 8; n++) {
            const ushort_t* wp = wbk_h + (qq*128 + n*16 + l16)*128 + quad*8;
#pragma unroll
            for (int ks = 0; ks < 4; ks++) {
                bf16x8 bw = *(const bf16x8*)(wp + ks*32);
                ab[n] = __builtin_amdgcn_mfma_f32_16x16x32_bf16(qa[ks], bw, ab[n], 0, 0, 0);
            }
        }
        asm volatile("" ::: "memory");
#pragma unroll
        for (int n = 0; n < 8; n++)
#pragma unroll
            for (int r = 0; r < 4; r++)
                paw[(tl + r)*136 + n*16 + l16] = f2bf(ab[n][r] * scale);
        asm volatile("" ::: "memory");
#pragma unroll
        for (int ks2 = 0; ks2 < 4; ks2++)
            qf[qq*4 + ks2] = *(const bf16x8*)(paw + l16*136 + ks2*32 + quad*8);
        asm volatile("" ::: "memory");
    }

#pragma unroll
    for (int kk = 0; kk < 2; kk++) {
        int off = kk*32 + quad*8;
        uint4 pv4 = *(const uint4*)(qrow + 128 + off);
        const ushort_t* pe = (const ushort_t*)&pv4;
        ushort_t pk[8];
#pragma unroll
        for (int u2 = 0; u2 < 4; u2++) {
            float xr = bf2f(pe[2*u2]), xi = bf2f(pe[2*u2+1]);
            int pi = (off >> 1) + u2;
            float c = cosT[rglob*32 + pi], sn = sinT[rglob*32 + pi];
            pk[2*u2]   = f2bf((xr*c  - xi*sn) * scale);
            pk[2*u2+1] = f2bf((xr*sn + xi*c ) * scale);
        }
        qf[16 + kk] = *(const bf16x8*)pk;
    }

    // ===== flash main loop, TK=32, no block barriers =====
    f32x4 o[32];
#pragma unroll
    for (int n = 0; n < 32; n++) o[n] = (f32x4)(0.f);
    float m_s = -1e30f, l_s = 0.f;

    const ushort_t* kvn_b = kvnb + (size_t)b*S_*512;
    const ushort_t* kpe_b = kpeb + (size_t)b*S_*64;
    const ushort_t* kvT_b = kvnT + (size_t)b*512*2048 + (size_t)l16*2048 + quad*8;

    const int niter = ((r0 + 15) >> 5) + 1;     // per-wave causal bound

#pragma unroll 1
    for (int it = 0; it < niter; it++) {
        const int t0 = it * 32;

        // S^T for two 16-key tiles: C col = q-row (l16), C row = key (tl+reg)
        f32x4 s0 = (f32x4)(0.f), s1 = (f32x4)(0.f);
        {
            const ushort_t* k0p = kvn_b + (size_t)(t0 + l16)*512 + quad*8;
            const ushort_t* k1p = k0p + 16*512;
#pragma unroll
            for (int ks = 0; ks < 16; ks++) {
                bf16x8 kf0 = *(const bf16x8*)(k0p + ks*32);
                s0 = __builtin_amdgcn_mfma_f32_16x16x32_bf16(kf0, qf[ks], s0, 0, 0, 0);
                bf16x8 kf1 = *(const bf16x8*)(k1p + ks*32);
                s1 = __builtin_amdgcn_mfma_f32_16x16x32_bf16(kf1, qf[ks], s1, 0, 0, 0);
            }
            const ushort_t* p0p = kpe_b + (size_t)(t0 + l16)*64 + quad*8;
            const ushort_t* p1p = p0p + 16*64;
#pragma unroll
            for (int ks = 0; ks < 2; ks++) {
                bf16x8 kf0 = *(const bf16x8*)(p0p + ks*32);
                s0 = __builtin_amdgcn_mfma_f32_16x16x32_bf16(kf0, qf[16+ks], s0, 0, 0, 0);
                bf16x8 kf1 = *(const bf16x8*)(p1p + ks*32);
                s1 = __builtin_amdgcn_mfma_f32_16x16x32_bf16(kf1, qf[16+ks], s1, 0, 0, 0);
            }
        }

        // online softmax for q-row rglob; lane holds keys t0+tl+reg, t0+16+tl+reg
        float pv[8];
        float mx = -1e30f;
#pragma unroll
        for (int reg = 0; reg < 4; reg++) {
            pv[reg]   = ((t0 + tl + reg)      <= rglob) ? s0[reg] : -1e30f;
            pv[4+reg] = ((t0 + 16 + tl + reg) <= rglob) ? s1[reg] : -1e30f;
            mx = fmaxf(mx, fmaxf(pv[reg], pv[4+reg]));
        }
        mx = fmaxf(mx, __shfl_xor(mx, 16));
        mx = fmaxf(mx, __shfl_xor(mx, 32));
        if (!__all(mx <= m_s)) {        // exact skip: al==1 when max unchanged
            float mn = fmaxf(m_s, mx);
            float al = __expf(m_s - mn);
            m_s = mn;
            l_s *= al;
            f32x4 alv;
#pragma unroll
            for (int reg = 0; reg < 4; reg++) alv[reg] = __shfl(al, lb + tl + reg, 64);
#pragma unroll
            for (int n = 0; n < 32; n++) o[n] *= alv;
        }
        float ps = 0.f;
#pragma unroll
        for (int reg = 0; reg < 8; reg++) {
            pv[reg] = (pv[reg] > -1e29f) ? __expf(pv[reg] - m_s) : 0.f;
            ps += pv[reg];
        }
        ps += __shfl_xor(ps, 16);
        ps += __shfl_xor(ps, 32);
        l_s += ps;

        // P^T -> ptw[r][t-local] (per-wave), fence, read back A-frag (k=32)
        ushort_t pk4[8];
#pragma unroll
        for (int reg = 0; reg < 8; reg++) pk4[reg] = f2bf(pv[reg]);
        *(uint2*)(ptw + l16*40 + tl)      = *(const uint2*)(pk4);
        *(uint2*)(ptw + l16*40 + 16 + tl) = *(const uint2*)(pk4 + 4);
        asm volatile("" ::: "memory");
        bf16x8 ap = *(const bf16x8*)(ptw + l16*40 + quad*8);
        asm volatile("" ::: "memory");

        // PV: o[n] += P[r][t] * V[t][c], c = n*16 + l16, V^T frags from L2
        const ushort_t* vp = kvT_b + t0;
#pragma unroll
        for (int n = 0; n < 32; n++) {
            bf16x8 bv = *(const bf16x8*)(vp + (size_t)n*16*2048);
            o[n] = __builtin_amdgcn_mfma_f32_16x16x32_bf16(ap, bv, o[n], 0, 0, 0);
        }
    }

    // ===== epilogue: out = (o/l) @ wbv^T, per-wave, full K=512 =====
    float linv = 1.f / l_s;
    f32x4 rlv;
#pragma unroll
    for (int reg = 0; reg < 4; reg++) rlv[reg] = __shfl(linv, lb + tl + reg, 64);

    const ushort_t* wbv_h = wbvB + h*65536;
    f32x4 acc2[8];
#pragma unroll
    for (int n2 = 0; n2 < 8; n2++) acc2[n2] = (f32x4)(0.f);

#pragma unroll
    for (int sub = 0; sub < 4; sub++) {
        asm volatile("" ::: "memory");
#pragma unroll
        for (int n = 0; n < 8; n++)
#pragma unroll
            for (int r = 0; r < 4; r++)
                paw[(tl + r)*136 + n*16 + l16] = f2bf(o[sub*8 + n][r] * rlv[r]);
        asm volatile("" ::: "memory");
#pragma unroll
        for (int ks = 0; ks < 4; ks++) {
            bf16x8 af = *(const bf16x8*)(paw + l16*136 + ks*32 + quad*8);
#pragma unroll
            for (int n2 = 0; n2 < 8; n2++) {
                bf16x8 bw = *(const bf16x8*)(wbv_h + (n2*16 + l16)*512 + sub*128 + ks*32 + quad*8);
                acc2[n2] = __builtin_amdgcn_mfma_f32_16x16x32_bf16(af, bw, acc2[n2], 0, 0, 0);
            }
        }
        asm volatile("" ::: "memory");
    }

    ushort_t* orow = ovb + (size_t)(b*S_ + r0)*2048 + h*128;
#pragma unroll
    for (int n2 = 0; n2 < 8; n2++)
#pragma unroll
        for (int reg = 0; reg < 4; reg++)
            orow[(size_t)(tl + reg)*2048 + n2*16 + l16] = f2bf(acc2[n2][reg]);
}

// ---------------------------------------------------------------------------
extern "C" void kernel_launch(void* const* d_in, const int* in_sizes, int n_in,
                              void* d_out, int out_size, void* d_ws, size_t ws_size,
                              hipStream_t stream) {
    const float* x     = (const float*)d_in[0];
    const float* cosT  = (const float*)d_in[1];
    const float* sinT  = (const float*)d_in[2];
    // d_in[3] mask: unused (causality applied directly)
    const float* wq    = (const float*)d_in[4];
    const float* wkv_a = (const float*)d_in[5];
    const float* kvw   = (const float*)d_in[6];
    const float* wkv_b = (const float*)d_in[7];
    const float* wo    = (const float*)d_in[8];
    float* out = (float*)d_out;

    ushort_t* qb   = (ushort_t*)d_ws;       // 4096x3072 bf16
    ushort_t* xb   = qb   + 12582912;       // 4096x2048
    ushort_t* wqb  = xb   + 8388608;        // 3072x2048
    ushort_t* wob  = wqb  + 6291456;        // 2048x2048
    ushort_t* ovb  = wob  + 4194304;        // 4096x2048
    ushort_t* kvnb = ovb  + 8388608;        // 4096x512
    ushort_t* kpeb = kvnb + 2097152;        // 4096x64
    ushort_t* kvnT = kpeb + 262144;         // 2x512x2048
    ushort_t* wbkT = kvnT + 2097152;        // 16x512x128
    ushort_t* wbvB = wbkT + 1048576;        // 16x128x512
    float*    kvr  = (float*)(wbvB + 1048576);  // 4096x576 f32

    dim3 blk(256);
    cast_bf16<<<dim3(8192), blk, 0, stream>>>(x,  xb,  8388608);
    cast_bf16<<<dim3(6144), blk, 0, stream>>>(wq, wqb, 6291456);
    cast_bf16<<<dim3(4096), blk, 0, stream>>>(wo, wob, 4194304);
    prep_wb<<<dim3(4096), blk, 0, stream>>>(wkv_b, wbkT, wbvB);
    gemm_bf16<<<dim3(3072/128, 4096/128), blk, 0, stream>>>(xb, wqb, nullptr, qb, 4096, 3072, 2048, 1);
    gemm_nt<<<dim3(576/64, 4096/64), blk, 0, stream>>>(x, wkv_a, kvr, 4096, 576, 2048, 2048, 2048, 576);
    kv_norm_rope<<<dim3(4096/4), blk, 0, stream>>>(kvr, kvw, cosT, sinT, kvnb, kvnT, kpeb);
    attn_mfma<<<dim3(S_/128, H_, B_), dim3(512), 0, stream>>>(qb, kvnb, kpeb, kvnT, cosT, sinT, wbkT, wbvB, ovb);
    gemm_bf16<<<dim3(2048/128, 4096/128), blk, 0, stream>>>(ovb, wob, out, nullptr, 4096, 2048, 2048, 0);
}

// Round 2
// 1201.901 us; speedup vs baseline: 2.5021x; 2.5021x over previous
//
#include <hip/hip_runtime.h>
#include <hip/hip_bf16.h>

// MLA forward, round 8: attention = r7 wave structure (16 unique rows/wave,
// TK=32, no duplicated S^T, no PV zero-pad) + block-shared double-buffered
// LDS staging via global_load_lds with lane-linear fragment layout
// (inverse-permuted global source addresses -> conflict-free ds_read_b128,
// bit-identical fragment values to r7). One __syncthreads per tile; stage of
// tile t+1 issued before compute of tile t. XCD swizzle: batch = flat&1 (one
// batch's KV per XCD L2), longest causal blocks dispatched first (LPT).
// B=2 S=2048 D=2048 H=16 NOPE=128 ROPE=64 V=128 C=512
#define B_ 2
#define S_ 2048
#define H_ 16

typedef unsigned short ushort_t;
typedef unsigned int uint_t;
typedef __attribute__((ext_vector_type(8))) short bf16x8;
typedef __attribute__((ext_vector_type(4))) float f32x4;

__device__ __forceinline__ ushort_t f2bf(float f) {
    uint_t u = __float_as_uint(f);
    return (ushort_t)((u + 0x7fffu + ((u >> 16) & 1u)) >> 16);
}
__device__ __forceinline__ float bf2f(ushort_t v) {
    return __uint_as_float(((uint_t)v) << 16);
}

// global -> LDS direct copy, 16B per lane. LDS dest must be wave-uniform;
// HW writes lane i at ldsbase + i*16. Global src is per-lane.
__device__ __forceinline__ void gl_lds16(const ushort_t* g, ushort_t* l) {
    __builtin_amdgcn_global_load_lds(
        (const __attribute__((address_space(1))) unsigned int*)(unsigned long long)g,
        (__attribute__((address_space(3))) unsigned int*)(unsigned int)(unsigned long long)l,
        16, 0, 0);
}

// ---------------------------------------------------------------------------
// f32 -> bf16 cast
// ---------------------------------------------------------------------------
__global__ __launch_bounds__(256) void cast_bf16(const float* __restrict__ src,
                                                 ushort_t* __restrict__ dst, int n)
{
    int i = (blockIdx.x * 256 + threadIdx.x) * 4;
    if (i < n) {
        float4 v = *(const float4*)(src + i);
        ushort_t pk[4] = { f2bf(v.x), f2bf(v.y), f2bf(v.z), f2bf(v.w) };
        *(uint2*)(dst + i) = *(const uint2*)pk;
    }
}

// ---------------------------------------------------------------------------
// bf16 MFMA GEMM: C[M,N] = A[M,K] @ B[N,K]^T. M,N %128==0, K%64==0.
// ---------------------------------------------------------------------------
__global__ __launch_bounds__(256, 2) void gemm_bf16(const ushort_t* __restrict__ A,
                                                    const ushort_t* __restrict__ Bm,
                                                    float* __restrict__ Cf,
                                                    ushort_t* __restrict__ Cb,
                                                    int M, int N, int K, int outBf)
{
    __shared__ __align__(16) ushort_t As[128*72];
    __shared__ __align__(16) ushort_t Bs[128*72];
    const int tid = threadIdx.x;
    const int wv = tid >> 6, lane = tid & 63, l16 = lane & 15, quad = lane >> 4;
    const int wm = wv >> 1, wn = wv & 1;
    const int m0 = blockIdx.y * 128, n0 = blockIdx.x * 128;
    const int row = tid >> 1, kh = (tid & 1) * 32;
    const ushort_t* Ag = A  + (size_t)(m0 + row) * K + kh;
    const ushort_t* Bg = Bm + (size_t)(n0 + row) * K + kh;

    f32x4 acc[16];
#pragma unroll
    for (int i = 0; i < 16; i++) acc[i] = (f32x4)(0.f);

    for (int k0 = 0; k0 < K; k0 += 64) {
        uint4 av[4], bv[4];
#pragma unroll
        for (int p = 0; p < 4; p++) {
            av[p] = *(const uint4*)(Ag + k0 + p*8);
            bv[p] = *(const uint4*)(Bg + k0 + p*8);
        }
        __syncthreads();
#pragma unroll
        for (int p = 0; p < 4; p++) {
            *(uint4*)(As + row*72 + kh + p*8) = av[p];
            *(uint4*)(Bs + row*72 + kh + p*8) = bv[p];
        }
        __syncthreads();
#pragma unroll
        for (int ks = 0; ks < 2; ks++) {
            bf16x8 af[4], bfr[4];
#pragma unroll
            for (int mt = 0; mt < 4; mt++)
                af[mt] = *(const bf16x8*)(As + (wm*64 + mt*16 + l16)*72 + ks*32 + quad*8);
#pragma unroll
            for (int nt = 0; nt < 4; nt++)
                bfr[nt] = *(const bf16x8*)(Bs + (wn*64 + nt*16 + l16)*72 + ks*32 + quad*8);
#pragma unroll
            for (int mt = 0; mt < 4; mt++)
#pragma unroll
                for (int nt = 0; nt < 4; nt++)
                    acc[mt*4+nt] = __builtin_amdgcn_mfma_f32_16x16x32_bf16(af[mt], bfr[nt], acc[mt*4+nt], 0, 0, 0);
        }
    }
#pragma unroll
    for (int mt = 0; mt < 4; mt++)
#pragma unroll
        for (int nt = 0; nt < 4; nt++)
#pragma unroll
            for (int r = 0; r < 4; r++) {
                size_t rr = m0 + wm*64 + mt*16 + quad*4 + r;
                int cc = n0 + wn*64 + nt*16 + l16;
                if (outBf) Cb[rr*N + cc] = f2bf(acc[mt*4+nt][r]);
                else       Cf[rr*N + cc] = acc[mt*4+nt][r];
            }
}

// ---------------------------------------------------------------------------
// f32 GEMM for kv-proj (kept f32 for rmsnorm accuracy).
// ---------------------------------------------------------------------------
__global__ __launch_bounds__(256) void gemm_nt(const float* __restrict__ A,
                                               const float* __restrict__ Bm,
                                               float* __restrict__ Cm,
                                               int M, int N, int K,
                                               int lda, int ldb, int ldc)
{
    __shared__ float As[16][68];
    __shared__ float Bs[16][68];
    const int tid = threadIdx.x;
    const int m0 = blockIdx.y * 64, n0 = blockIdx.x * 64;
    const int lr = tid >> 2;
    const int lc = (tid & 3) << 2;
    const int ty = tid >> 4, tx = tid & 15;
    const float* Ag = A  + (m0 + lr) * lda + lc;
    const float* Bg = Bm + (n0 + lr) * ldb + lc;

    float acc[4][4];
#pragma unroll
    for (int i = 0; i < 4; i++)
#pragma unroll
        for (int j = 0; j < 4; j++) acc[i][j] = 0.f;

    for (int k0 = 0; k0 < K; k0 += 16) {
        float4 av = *(const float4*)(Ag + k0);
        float4 bv = *(const float4*)(Bg + k0);
        __syncthreads();
        As[lc+0][lr] = av.x; As[lc+1][lr] = av.y; As[lc+2][lr] = av.z; As[lc+3][lr] = av.w;
        Bs[lc+0][lr] = bv.x; Bs[lc+1][lr] = bv.y; Bs[lc+2][lr] = bv.z; Bs[lc+3][lr] = bv.w;
        __syncthreads();
#pragma unroll
        for (int kk = 0; kk < 16; kk++) {
            float4 a = *(const float4*)&As[kk][ty*4];
            float4 b = *(const float4*)&Bs[kk][tx*4];
            acc[0][0] += a.x*b.x; acc[0][1] += a.x*b.y; acc[0][2] += a.x*b.z; acc[0][3] += a.x*b.w;
            acc[1][0] += a.y*b.x; acc[1][1] += a.y*b.y; acc[1][2] += a.y*b.z; acc[1][3] += a.y*b.w;
            acc[2][0] += a.z*b.x; acc[2][1] += a.z*b.y; acc[2][2] += a.z*b.z; acc[2][3] += a.z*b.w;
            acc[3][0] += a.w*b.x; acc[3][1] += a.w*b.y; acc[3][2] += a.w*b.z; acc[3][3] += a.w*b.w;
        }
    }
#pragma unroll
    for (int i = 0; i < 4; i++) {
        float4 r; r.x = acc[i][0]; r.y = acc[i][1]; r.z = acc[i][2]; r.w = acc[i][3];
        *(float4*)(Cm + (m0 + ty*4 + i) * ldc + n0 + tx*4) = r;
    }
}

// ---------------------------------------------------------------------------
__global__ __launch_bounds__(256) void prep_wb(const float* __restrict__ wkv_b,
                                               ushort_t* __restrict__ wbkT,
                                               ushort_t* __restrict__ wbvB)
{
    int u = blockIdx.x * 256 + threadIdx.x;
    {
        int h = u >> 16, rem = u & 65535, c = rem >> 7, d = rem & 127;
        wbkT[u] = f2bf(wkv_b[h*131072 + d*512 + c]);
    }
    {
        int h = u >> 16, rem = u & 65535;
        wbvB[u] = f2bf(wkv_b[h*131072 + 65536 + rem]);
    }
}

// ---------------------------------------------------------------------------
__global__ __launch_bounds__(256) void kv_norm_rope(const float* __restrict__ kvr,
                                                    const float* __restrict__ w,
                                                    const float* __restrict__ cosT,
                                                    const float* __restrict__ sinT,
                                                    ushort_t* __restrict__ kvnb,
                                                    ushort_t* __restrict__ kvnT,
                                                    ushort_t* __restrict__ kpeb)
{
    const int bs   = blockIdx.x * 4 + (threadIdx.x >> 6);
    const int lane = threadIdx.x & 63;
    const int s    = bs & (S_ - 1);
    const float* row = kvr + bs * 576;

    float4 v0 = *(const float4*)(row + lane*8);
    float4 v1 = *(const float4*)(row + lane*8 + 4);
    float ss = v0.x*v0.x + v0.y*v0.y + v0.z*v0.z + v0.w*v0.w
             + v1.x*v1.x + v1.y*v1.y + v1.z*v1.z + v1.w*v1.w;
#pragma unroll
    for (int off = 32; off >= 1; off >>= 1) ss += __shfl_xor(ss, off);
    const float rs = rsqrtf(ss * (1.0f/512.0f) + 1e-6f);

    float4 w0 = *(const float4*)(w + lane*8);
    float4 w1 = *(const float4*)(w + lane*8 + 4);
    float o[8];
    o[0] = v0.x*rs*w0.x; o[1] = v0.y*rs*w0.y; o[2] = v0.z*rs*w0.z; o[3] = v0.w*rs*w0.w;
    o[4] = v1.x*rs*w1.x; o[5] = v1.y*rs*w1.y; o[6] = v1.z*rs*w1.z; o[7] = v1.w*rs*w1.w;

    ushort_t pk[8];
#pragma unroll
    for (int p = 0; p < 8; p++) pk[p] = f2bf(o[p]);
    *(uint4*)(kvnb + (size_t)bs*512 + lane*8) = *(const uint4*)pk;

    const int bb = bs >> 11, t = bs & 2047;
    ushort_t* base = kvnT + ((size_t)(bb*512 + lane*8))*2048 + t;
#pragma unroll
    for (int k = 0; k < 8; k++) base[k*2048] = pk[k];

    if (lane < 32) {
        float xr = row[512 + 2*lane], xi = row[512 + 2*lane + 1];
        float c  = cosT[s*32 + lane], sn = sinT[s*32 + lane];
        ushort_t p2[2] = { f2bf(xr*c - xi*sn), f2bf(xr*sn + xi*c) };
        *(uint_t*)(kpeb + (size_t)bs*64 + 2*lane) = *(const uint_t*)p2;
    }
}

// ---------------------------------------------------------------------------
// stage one 32-key tile: K (2304 chunks) -> F[buf], V^T (2048 chunks) -> G[buf]
// lane-linear frag layout; each wave issues its i%8==w subset.
// ---------------------------------------------------------------------------
__device__ __forceinline__ void stage_tile(const ushort_t* kvn_b, const ushort_t* kpe_b,
                                           const ushort_t* kvT_b, ushort_t* ldsb,
                                           int t0, int buf, int w, int l16, int q8e)
{
    ushort_t* Fb = ldsb + buf*18432;
    ushort_t* Gb = ldsb + 36864 + buf*16384;
#pragma unroll
    for (int ii = 0; ii < 5; ii++) {
        int i = w + ii*8;
        if (i < 36) {
            int g2 = (i >= 18) ? 1 : 0;
            int ks = i - g2*18;
            int row = t0 + g2*16 + l16;
            const ushort_t* src = (ks < 16)
                ? (kvn_b + (size_t)row*512 + ks*32 + q8e)
                : (kpe_b + (size_t)row*64 + (ks-16)*32 + q8e);
            gl_lds16(src, Fb + i*512);
        }
    }
#pragma unroll
    for (int ii = 0; ii < 4; ii++) {
        int i = w + ii*8;
        const ushort_t* src = kvT_b + (size_t)(i*16 + l16)*2048 + t0 + q8e;
        gl_lds16(src, Gb + i*512);
    }
}

// ---------------------------------------------------------------------------
// MFMA flash attention v6: 128 q-rows/block, 8 waves x 16 unique rows, TK=32,
// double-buffered LDS K/V tiles staged via global_load_lds, 1 barrier/tile.
// ---------------------------------------------------------------------------
__global__ __launch_bounds__(512, 2) void attn_mfma(
    const ushort_t* __restrict__ qb,
    const ushort_t* __restrict__ kvnb,
    const ushort_t* __restrict__ kpeb,
    const ushort_t* __restrict__ kvnT,
    const float* __restrict__ cosT,
    const float* __restrict__ sinT,
    const ushort_t* __restrict__ wbkT,
    const ushort_t* __restrict__ wbvB,
    ushort_t* __restrict__ ovb)
{
    // XCD/LPT swizzle: batch = flat&1 (one batch per XCD-L2), longest blocks first
    const int flat = blockIdx.x + 16*blockIdx.y + 256*blockIdx.z;
    const int b    = flat & 1;
    const int rem  = flat >> 1;
    const int h    = rem & 15;
    const int q0   = (15 - (rem >> 4)) << 7;

    const int tid  = threadIdx.x;
    const int w    = tid >> 6;
    const int lane = tid & 63;
    const int l16  = lane & 15;
    const int quad = lane >> 4;
    const int tl   = quad * 4;
    const int lb   = lane & 48;
    const int q8e  = quad * 8;
    const float scale = 0.07216878364870323f;   // 192^-0.5

    // LDS map (ushort elems):
    //   F[buf] = buf*18432        : [g2][ks 0..17][lane][8]  (36 KB x2)
    //   G[buf] = 36864 + buf*16384: [n 0..31][lane][8]       (32 KB x2)
    //   pt     = 69632 + w*640    : per-wave 16x40 P^T scratch
    //   phase-A scr overlay = 18432 + w*2176 (inside F[1], dead before loop)
    __shared__ __align__(16) ushort_t lds[74752];

    const ushort_t* kvn_b = kvnb + (size_t)b*S_*512;
    const ushort_t* kpe_b = kpeb + (size_t)b*S_*64;
    const ushort_t* kvT_b = kvnT + (size_t)b*512*2048;

    const int r0    = q0 + w*16;
    const int rglob = r0 + l16;

    // ---- prologue: stage tile 0 into buf 0 (latency hides under phase A)
    stage_tile(kvn_b, kpe_b, kvT_b, lds, 0, 0, w, l16, q8e);

    // ===== phase A: build q_abs*scale as B-frags qf[0..15], pe -> qf[16..17]
    ushort_t* paw = lds + 18432 + w*2176;
    const ushort_t* qrow = qb + (size_t)(b*S_ + rglob)*3072 + h*192;
    bf16x8 qa[4], qf[18];
#pragma unroll
    for (int ks = 0; ks < 4; ks++)
        qa[ks] = *(const bf16x8*)(qrow + ks*32 + q8e);

    const ushort_t* wbk_h = wbkT + h*65536;
#pragma unroll
    for (int qq = 0; qq < 4; qq++) {
        f32x4 ab[8];
#pragma unroll
        for (int n = 0; n < 8; n++) ab[n] = (f32x4)(0.f);
#pragma unroll
        for (int n = 0; n < 8; n++) {
            const ushort_t* wp = wbk_h + (qq*128 + n*16 + l16)*128 + q8e;
#pragma unroll
            for (int ks = 0; ks < 4; ks++) {
                bf16x8 bw = *(const bf16x8*)(wp + ks*32);
                ab[n] = __builtin_amdgcn_mfma_f32_16x16x32_bf16(qa[ks], bw, ab[n], 0, 0, 0);
            }
        }
        asm volatile("" ::: "memory");
#pragma unroll
        for (int n = 0; n < 8; n++)
#pragma unroll
            for (int r = 0; r < 4; r++)
                paw[(tl + r)*136 + n*16 + l16] = f2bf(ab[n][r] * scale);
        asm volatile("" ::: "memory");
#pragma unroll
        for (int ks2 = 0; ks2 < 4; ks2++)
            qf[qq*4 + ks2] = *(const bf16x8*)(paw + l16*136 + ks2*32 + q8e);
        asm volatile("" ::: "memory");
    }

#pragma unroll
    for (int kk = 0; kk < 2; kk++) {
        int off = kk*32 + q8e;
        uint4 pv4 = *(const uint4*)(qrow + 128 + off);
        const ushort_t* pe = (const ushort_t*)&pv4;
        ushort_t pk[8];
#pragma unroll
        for (int u2 = 0; u2 < 4; u2++) {
            float xr = bf2f(pe[2*u2]), xi = bf2f(pe[2*u2+1]);
            int pi = (off >> 1) + u2;
            float c = cosT[rglob*32 + pi], sn = sinT[rglob*32 + pi];
            pk[2*u2]   = f2bf((xr*c  - xi*sn) * scale);
            pk[2*u2+1] = f2bf((xr*sn + xi*c ) * scale);
        }
        qf[16 + kk] = *(const bf16x8*)pk;
    }
    __syncthreads();   // phase-A LDS done + tile0 staging drained

    // ===== flash main loop: TK=32, double-buffered, 1 barrier/tile =====
    f32x4 o[32];
#pragma unroll
    for (int n = 0; n < 32; n++) o[n] = (f32x4)(0.f);
    float m_s = -1e30f, l_s = 0.f;

    const int bniter = (q0 >> 5) + 4;            // block-uniform tile count
    const int wniter = ((r0 + 15) >> 5) + 1;     // this wave's causal bound
    ushort_t* ptw = lds + 69632 + w*640;
    int cur = 0;

#pragma unroll 1
    for (int it = 0; it < bniter; it++) {
        if (it + 1 < bniter)
            stage_tile(kvn_b, kpe_b, kvT_b, lds, (it+1)*32, cur ^ 1, w, l16, q8e);

        if (it < wniter) {
            const int t0 = it * 32;
            const ushort_t* Fb = lds + cur*18432;
            const ushort_t* Gb = lds + 36864 + cur*16384;

            // S^T: C col = q-row (l16), C row = key (tl+reg); two 16-key groups
            f32x4 s0 = (f32x4)(0.f), s1 = (f32x4)(0.f);
#pragma unroll
            for (int ks = 0; ks < 18; ks++) {
                bf16x8 kf0 = *(const bf16x8*)(Fb + ks*512 + lane*8);
                s0 = __builtin_amdgcn_mfma_f32_16x16x32_bf16(kf0, qf[ks], s0, 0, 0, 0);
                bf16x8 kf1 = *(const bf16x8*)(Fb + 9216 + ks*512 + lane*8);
                s1 = __builtin_amdgcn_mfma_f32_16x16x32_bf16(kf1, qf[ks], s1, 0, 0, 0);
            }

            // online softmax for q-row rglob
            float pv[8];
            float mx = -1e30f;
#pragma unroll
            for (int reg = 0; reg < 4; reg++) {
                pv[reg]   = ((t0 + tl + reg)      <= rglob) ? s0[reg] : -1e30f;
                pv[4+reg] = ((t0 + 16 + tl + reg) <= rglob) ? s1[reg] : -1e30f;
                mx = fmaxf(mx, fmaxf(pv[reg], pv[4+reg]));
            }
            mx = fmaxf(mx, __shfl_xor(mx, 16));
            mx = fmaxf(mx, __shfl_xor(mx, 32));
            if (!__all(mx <= m_s)) {        // exact skip when max unchanged
                float mn = fmaxf(m_s, mx);
                float al = __expf(m_s - mn);
                m_s = mn;
                l_s *= al;
                f32x4 alv;
#pragma unroll
                for (int reg = 0; reg < 4; reg++) alv[reg] = __shfl(al, lb + tl + reg, 64);
#pragma unroll
                for (int n = 0; n < 32; n++) o[n] *= alv;
            }
            float ps = 0.f;
#pragma unroll
            for (int reg = 0; reg < 8; reg++) {
                pv[reg] = (pv[reg] > -1e29f) ? __expf(pv[reg] - m_s) : 0.f;
                ps += pv[reg];
            }
            ps += __shfl_xor(ps, 16);
            ps += __shfl_xor(ps, 32);
            l_s += ps;

            // P^T -> ptw (per-wave), fence, read back A-frag (k=32)
            ushort_t pk4[8];
#pragma unroll
            for (int reg = 0; reg < 8; reg++) pk4[reg] = f2bf(pv[reg]);
            *(uint2*)(ptw + l16*40 + tl)      = *(const uint2*)(pk4);
            *(uint2*)(ptw + l16*40 + 16 + tl) = *(const uint2*)(pk4 + 4);
            asm volatile("" ::: "memory");
            bf16x8 ap = *(const bf16x8*)(ptw + l16*40 + q8e);
            asm volatile("" ::: "memory");

            // PV: o[n] += P[r][t] * V[t][c], c = n*16 + l16
#pragma unroll
            for (int n = 0; n < 32; n++) {
                bf16x8 bv = *(const bf16x8*)(Gb + n*512 + lane*8);
                o[n] = __builtin_amdgcn_mfma_f32_16x16x32_bf16(ap, bv, o[n], 0, 0, 0);
            }
        }
        __syncthreads();   // next-tile staging drained + cur-buffer reads done
        cur ^= 1;
    }

    // ===== epilogue: out = (o/l) @ wbv^T, per-wave, full K=512 =====
    float linv = 1.f / l_s;
    f32x4 rlv;
#pragma unroll
    for (int reg = 0; reg < 4; reg++) rlv[reg] = __shfl(linv, lb + tl + reg, 64);

    const ushort_t* wbv_h = wbvB + h*65536;
    f32x4 acc2[8];
#pragma unroll
    for (int n2 = 0; n2 < 8; n2++) acc2[n2] = (f32x4)(0.f);

#pragma unroll
    for (int sub = 0; sub < 4; sub++) {
        asm volatile("" ::: "memory");
#pragma unroll
        for (int n = 0; n < 8; n++)
#pragma unroll
            for (int r = 0; r < 4; r++)
                paw[(tl + r)*136 + n*16 + l16] = f2bf(o[sub*8 + n][r] * rlv[r]);
        asm volatile("" ::: "memory");
#pragma unroll
        for (int ks = 0; ks < 4; ks++) {
            bf16x8 af = *(const bf16x8*)(paw + l16*136 + ks*32 + q8e);
#pragma unroll
            for (int n2 = 0; n2 < 8; n2++) {
                bf16x8 bw = *(const bf16x8*)(wbv_h + (n2*16 + l16)*512 + sub*128 + ks*32 + q8e);
                acc2[n2] = __builtin_amdgcn_mfma_f32_16x16x32_bf16(af, bw, acc2[n2], 0, 0, 0);
            }
        }
        asm volatile("" ::: "memory");
    }

    ushort_t* orow = ovb + (size_t)(b*S_ + r0)*2048 + h*128;
#pragma unroll
    for (int n2 = 0; n2 < 8; n2++)
#pragma unroll
        for (int reg = 0; reg < 4; reg++)
            orow[(size_t)(tl + reg)*2048 + n2*16 + l16] = f2bf(acc2[n2][reg]);
}

// ---------------------------------------------------------------------------
extern "C" void kernel_launch(void* const* d_in, const int* in_sizes, int n_in,
                              void* d_out, int out_size, void* d_ws, size_t ws_size,
                              hipStream_t stream) {
    const float* x     = (const float*)d_in[0];
    const float* cosT  = (const float*)d_in[1];
    const float* sinT  = (const float*)d_in[2];
    // d_in[3] mask: unused (causality applied directly)
    const float* wq    = (const float*)d_in[4];
    const float* wkv_a = (const float*)d_in[5];
    const float* kvw   = (const float*)d_in[6];
    const float* wkv_b = (const float*)d_in[7];
    const float* wo    = (const float*)d_in[8];
    float* out = (float*)d_out;

    ushort_t* qb   = (ushort_t*)d_ws;       // 4096x3072 bf16
    ushort_t* xb   = qb   + 12582912;       // 4096x2048
    ushort_t* wqb  = xb   + 8388608;        // 3072x2048
    ushort_t* wob  = wqb  + 6291456;        // 2048x2048
    ushort_t* ovb  = wob  + 4194304;        // 4096x2048
    ushort_t* kvnb = ovb  + 8388608;        // 4096x512
    ushort_t* kpeb = kvnb + 2097152;        // 4096x64
    ushort_t* kvnT = kpeb + 262144;         // 2x512x2048
    ushort_t* wbkT = kvnT + 2097152;        // 16x512x128
    ushort_t* wbvB = wbkT + 1048576;        // 16x128x512
    float*    kvr  = (float*)(wbvB + 1048576);  // 4096x576 f32

    dim3 blk(256);
    cast_bf16<<<dim3(8192), blk, 0, stream>>>(x,  xb,  8388608);
    cast_bf16<<<dim3(6144), blk, 0, stream>>>(wq, wqb, 6291456);
    cast_bf16<<<dim3(4096), blk, 0, stream>>>(wo, wob, 4194304);
    prep_wb<<<dim3(4096), blk, 0, stream>>>(wkv_b, wbkT, wbvB);
    gemm_bf16<<<dim3(3072/128, 4096/128), blk, 0, stream>>>(xb, wqb, nullptr, qb, 4096, 3072, 2048, 1);
    gemm_nt<<<dim3(576/64, 4096/64), blk, 0, stream>>>(x, wkv_a, kvr, 4096, 576, 2048, 2048, 2048, 576);
    kv_norm_rope<<<dim3(4096/4), blk, 0, stream>>>(kvr, kvw, cosT, sinT, kvnb, kvnT, kpeb);
    attn_mfma<<<dim3(S_/128, H_, B_), dim3(512), 0, stream>>>(qb, kvnb, kpeb, kvnT, cosT, sinT, wbkT, wbvB, ovb);
    gemm_bf16<<<dim3(2048/128, 4096/128), blk, 0, stream>>>(ovb, wob, out, nullptr, 4096, 2048, 2048, 0);
}

// Round 3
// 645.969 us; speedup vs baseline: 4.6555x; 1.8606x over previous
//
#include <hip/hip_runtime.h>
#include <hip/hip_bf16.h>

// MLA forward, round 9:
//  - V' folding: precompute V'[b,h] = kvn @ wbv[h]^T (gemm_vp, stored transposed
//    [b][h][c][t] = vpT, aliases dead xb buffer). Attention PV shrinks from
//    o[32]/32 MFMA/32KB-LDS per wave-tile to o[8]/8 MFMA/8KB, epilogue GEMM
//    deleted, ~96 VGPRs freed. kvnT + its scatter writes deleted.
//  - gemm_bf16 rebuilt m97-style: global_load_lds width-16 staging, double
//    buffered, 1 barrier per k-step, chunk-XOR swizzle (row&7) applied on the
//    per-lane global source AND the ds_read address (conflict-free b128).
// B=2 S=2048 D=2048 H=16 NOPE=128 ROPE=64 V=128 C=512
#define B_ 2
#define S_ 2048
#define H_ 16

typedef unsigned short ushort_t;
typedef unsigned int uint_t;
typedef __attribute__((ext_vector_type(8))) short bf16x8;
typedef __attribute__((ext_vector_type(4))) float f32x4;

__device__ __forceinline__ ushort_t f2bf(float f) {
    uint_t u = __float_as_uint(f);
    return (ushort_t)((u + 0x7fffu + ((u >> 16) & 1u)) >> 16);
}
__device__ __forceinline__ float bf2f(ushort_t v) {
    return __uint_as_float(((uint_t)v) << 16);
}

// global -> LDS direct copy, 16B per lane. LDS dest wave-uniform; HW writes
// lane i at ldsbase + i*16. Global src per-lane.
__device__ __forceinline__ void gl_lds16(const ushort_t* g, ushort_t* l) {
    __builtin_amdgcn_global_load_lds(
        (const __attribute__((address_space(1))) unsigned int*)(unsigned long long)g,
        (__attribute__((address_space(3))) unsigned int*)(unsigned int)(unsigned long long)l,
        16, 0, 0);
}

// ---------------------------------------------------------------------------
// f32 -> bf16 cast
// ---------------------------------------------------------------------------
__global__ __launch_bounds__(256) void cast_bf16(const float* __restrict__ src,
                                                 ushort_t* __restrict__ dst, int n)
{
    int i = (blockIdx.x * 256 + threadIdx.x) * 4;
    if (i < n) {
        float4 v = *(const float4*)(src + i);
        ushort_t pk[4] = { f2bf(v.x), f2bf(v.y), f2bf(v.z), f2bf(v.w) };
        *(uint2*)(dst + i) = *(const uint2*)pk;
    }
}

// ---------------------------------------------------------------------------
// bf16 MFMA GEMM (m97-style): C[M,N] = A[M,K] @ B[N,K]^T. M,N%128==0, K%64==0.
// global_load_lds staging, double-buffered, chunk-XOR swizzle.
// ---------------------------------------------------------------------------
__global__ __launch_bounds__(256, 2) void gemm_bf16(const ushort_t* __restrict__ A,
                                                    const ushort_t* __restrict__ Bm,
                                                    float* __restrict__ Cf,
                                                    ushort_t* __restrict__ Cb,
                                                    int M, int N, int K, int outBf)
{
    __shared__ __align__(16) ushort_t As[2][8192];
    __shared__ __align__(16) ushort_t Bs[2][8192];
    const int tid = threadIdx.x;
    const int wv = tid >> 6, lane = tid & 63, l16 = lane & 15, quad = lane >> 4;
    const int wm = wv >> 1, wn = wv & 1;
    const int m0 = blockIdx.y * 128, n0 = blockIdx.x * 128;
    const int srow = lane >> 3;                  // 0..7 within 8-row chunk
    const int sch  = ((lane & 7) ^ srow) * 8;    // swizzled source chunk (ushorts)

    f32x4 acc[16];
#pragma unroll
    for (int i = 0; i < 16; i++) acc[i] = (f32x4)(0.f);

    // prologue: stage k0=0 into buf 0
#pragma unroll
    for (int p = 0; p < 4; p++) {
        int g = wv + p*4, row = g*8 + srow;
        gl_lds16(A  + (size_t)(m0 + row) * K + sch, &As[0][g*512]);
        gl_lds16(Bm + (size_t)(n0 + row) * K + sch, &Bs[0][g*512]);
    }
    __syncthreads();

    int cur = 0;
    for (int k0 = 0; k0 < K; k0 += 64) {
        if (k0 + 64 < K) {
#pragma unroll
            for (int p = 0; p < 4; p++) {
                int g = wv + p*4, row = g*8 + srow;
                gl_lds16(A  + (size_t)(m0 + row) * K + k0 + 64 + sch, &As[cur^1][g*512]);
                gl_lds16(Bm + (size_t)(n0 + row) * K + k0 + 64 + sch, &Bs[cur^1][g*512]);
            }
        }
#pragma unroll
        for (int ks = 0; ks < 2; ks++) {
            bf16x8 af[4], bfr[4];
#pragma unroll
            for (int mt = 0; mt < 4; mt++) {
                int row = wm*64 + mt*16 + l16;
                af[mt] = *(const bf16x8*)(&As[cur][row*64 + (((ks*4+quad) ^ (l16&7))*8)]);
            }
#pragma unroll
            for (int nt = 0; nt < 4; nt++) {
                int row = wn*64 + nt*16 + l16;
                bfr[nt] = *(const bf16x8*)(&Bs[cur][row*64 + (((ks*4+quad) ^ (l16&7))*8)]);
            }
#pragma unroll
            for (int mt = 0; mt < 4; mt++)
#pragma unroll
                for (int nt = 0; nt < 4; nt++)
                    acc[mt*4+nt] = __builtin_amdgcn_mfma_f32_16x16x32_bf16(af[mt], bfr[nt], acc[mt*4+nt], 0, 0, 0);
        }
        __syncthreads();
        cur ^= 1;
    }
#pragma unroll
    for (int mt = 0; mt < 4; mt++)
#pragma unroll
        for (int nt = 0; nt < 4; nt++)
#pragma unroll
            for (int r = 0; r < 4; r++) {
                size_t rr = m0 + wm*64 + mt*16 + quad*4 + r;
                int cc = n0 + wn*64 + nt*16 + l16;
                if (outBf) Cb[rr*N + cc] = f2bf(acc[mt*4+nt][r]);
                else       Cf[rr*N + cc] = acc[mt*4+nt][r];
            }
}

// ---------------------------------------------------------------------------
// V' GEMM: vpT[b][h][c][t] = sum_k kvn[b,t,k] * wbv[h,c,k]. Tile 128x128, K=512.
// ---------------------------------------------------------------------------
__global__ __launch_bounds__(256, 2) void gemm_vp(const ushort_t* __restrict__ kvnb,
                                                  const ushort_t* __restrict__ wbvB,
                                                  ushort_t* __restrict__ vpT)
{
    __shared__ __align__(16) ushort_t As[2][8192];
    __shared__ __align__(16) ushort_t Bs[2][8192];
    const int tid = threadIdx.x;
    const int wv = tid >> 6, lane = tid & 63, l16 = lane & 15, quad = lane >> 4;
    const int wm = wv >> 1, wn = wv & 1;
    const int m0 = blockIdx.x * 128;
    const int h  = blockIdx.y;
    const ushort_t* Bh = wbvB + h*65536;
    const int srow = lane >> 3;
    const int sch  = ((lane & 7) ^ srow) * 8;

    f32x4 acc[16];
#pragma unroll
    for (int i = 0; i < 16; i++) acc[i] = (f32x4)(0.f);

#pragma unroll
    for (int p = 0; p < 4; p++) {
        int g = wv + p*4, row = g*8 + srow;
        gl_lds16(kvnb + (size_t)(m0 + row)*512 + sch, &As[0][g*512]);
        gl_lds16(Bh   + (size_t)row*512 + sch,        &Bs[0][g*512]);
    }
    __syncthreads();

    int cur = 0;
    for (int k0 = 0; k0 < 512; k0 += 64) {
        if (k0 + 64 < 512) {
#pragma unroll
            for (int p = 0; p < 4; p++) {
                int g = wv + p*4, row = g*8 + srow;
                gl_lds16(kvnb + (size_t)(m0 + row)*512 + k0 + 64 + sch, &As[cur^1][g*512]);
                gl_lds16(Bh   + (size_t)row*512 + k0 + 64 + sch,        &Bs[cur^1][g*512]);
            }
        }
#pragma unroll
        for (int ks = 0; ks < 2; ks++) {
            bf16x8 af[4], bfr[4];
#pragma unroll
            for (int mt = 0; mt < 4; mt++) {
                int row = wm*64 + mt*16 + l16;
                af[mt] = *(const bf16x8*)(&As[cur][row*64 + (((ks*4+quad) ^ (l16&7))*8)]);
            }
#pragma unroll
            for (int nt = 0; nt < 4; nt++) {
                int row = wn*64 + nt*16 + l16;
                bfr[nt] = *(const bf16x8*)(&Bs[cur][row*64 + (((ks*4+quad) ^ (l16&7))*8)]);
            }
#pragma unroll
            for (int mt = 0; mt < 4; mt++)
#pragma unroll
                for (int nt = 0; nt < 4; nt++)
                    acc[mt*4+nt] = __builtin_amdgcn_mfma_f32_16x16x32_bf16(af[mt], bfr[nt], acc[mt*4+nt], 0, 0, 0);
        }
        __syncthreads();
        cur ^= 1;
    }
    // scatter: 4 consecutive t per lane -> uint2
#pragma unroll
    for (int mt = 0; mt < 4; mt++)
#pragma unroll
        for (int nt = 0; nt < 4; nt++) {
            int rr = m0 + wm*64 + mt*16 + quad*4;
            int bb = rr >> 11, t = rr & 2047;
            int cc = wn*64 + nt*16 + l16;
            ushort_t pk[4];
#pragma unroll
            for (int r = 0; r < 4; r++) pk[r] = f2bf(acc[mt*4+nt][r]);
            *(uint2*)(vpT + ((size_t)((bb*16 + h)*128 + cc))*2048 + t) = *(const uint2*)pk;
        }
}

// ---------------------------------------------------------------------------
// f32 GEMM for kv-proj (kept f32 for rmsnorm accuracy).
// ---------------------------------------------------------------------------
__global__ __launch_bounds__(256) void gemm_nt(const float* __restrict__ A,
                                               const float* __restrict__ Bm,
                                               float* __restrict__ Cm,
                                               int M, int N, int K,
                                               int lda, int ldb, int ldc)
{
    __shared__ float As[16][68];
    __shared__ float Bs[16][68];
    const int tid = threadIdx.x;
    const int m0 = blockIdx.y * 64, n0 = blockIdx.x * 64;
    const int lr = tid >> 2;
    const int lc = (tid & 3) << 2;
    const int ty = tid >> 4, tx = tid & 15;
    const float* Ag = A  + (m0 + lr) * lda + lc;
    const float* Bg = Bm + (n0 + lr) * ldb + lc;

    float acc[4][4];
#pragma unroll
    for (int i = 0; i < 4; i++)
#pragma unroll
        for (int j = 0; j < 4; j++) acc[i][j] = 0.f;

    for (int k0 = 0; k0 < K; k0 += 16) {
        float4 av = *(const float4*)(Ag + k0);
        float4 bv = *(const float4*)(Bg + k0);
        __syncthreads();
        As[lc+0][lr] = av.x; As[lc+1][lr] = av.y; As[lc+2][lr] = av.z; As[lc+3][lr] = av.w;
        Bs[lc+0][lr] = bv.x; Bs[lc+1][lr] = bv.y; Bs[lc+2][lr] = bv.z; Bs[lc+3][lr] = bv.w;
        __syncthreads();
#pragma unroll
        for (int kk = 0; kk < 16; kk++) {
            float4 a = *(const float4*)&As[kk][ty*4];
            float4 b = *(const float4*)&Bs[kk][tx*4];
            acc[0][0] += a.x*b.x; acc[0][1] += a.x*b.y; acc[0][2] += a.x*b.z; acc[0][3] += a.x*b.w;
            acc[1][0] += a.y*b.x; acc[1][1] += a.y*b.y; acc[1][2] += a.y*b.z; acc[1][3] += a.y*b.w;
            acc[2][0] += a.z*b.x; acc[2][1] += a.z*b.y; acc[2][2] += a.z*b.z; acc[2][3] += a.z*b.w;
            acc[3][0] += a.w*b.x; acc[3][1] += a.w*b.y; acc[3][2] += a.w*b.z; acc[3][3] += a.w*b.w;
        }
    }
#pragma unroll
    for (int i = 0; i < 4; i++) {
        float4 r; r.x = acc[i][0]; r.y = acc[i][1]; r.z = acc[i][2]; r.w = acc[i][3];
        *(float4*)(Cm + (m0 + ty*4 + i) * ldc + n0 + tx*4) = r;
    }
}

// ---------------------------------------------------------------------------
__global__ __launch_bounds__(256) void prep_wb(const float* __restrict__ wkv_b,
                                               ushort_t* __restrict__ wbkT,
                                               ushort_t* __restrict__ wbvB)
{
    int u = blockIdx.x * 256 + threadIdx.x;
    {
        int h = u >> 16, rem = u & 65535, c = rem >> 7, d = rem & 127;
        wbkT[u] = f2bf(wkv_b[h*131072 + d*512 + c]);
    }
    {
        int h = u >> 16, rem = u & 65535;
        wbvB[u] = f2bf(wkv_b[h*131072 + 65536 + rem]);
    }
}

// ---------------------------------------------------------------------------
__global__ __launch_bounds__(256) void kv_norm_rope(const float* __restrict__ kvr,
                                                    const float* __restrict__ w,
                                                    const float* __restrict__ cosT,
                                                    const float* __restrict__ sinT,
                                                    ushort_t* __restrict__ kvnb,
                                                    ushort_t* __restrict__ kpeb)
{
    const int bs   = blockIdx.x * 4 + (threadIdx.x >> 6);
    const int lane = threadIdx.x & 63;
    const int s    = bs & (S_ - 1);
    const float* row = kvr + bs * 576;

    float4 v0 = *(const float4*)(row + lane*8);
    float4 v1 = *(const float4*)(row + lane*8 + 4);
    float ss = v0.x*v0.x + v0.y*v0.y + v0.z*v0.z + v0.w*v0.w
             + v1.x*v1.x + v1.y*v1.y + v1.z*v1.z + v1.w*v1.w;
#pragma unroll
    for (int off = 32; off >= 1; off >>= 1) ss += __shfl_xor(ss, off);
    const float rs = rsqrtf(ss * (1.0f/512.0f) + 1e-6f);

    float4 w0 = *(const float4*)(w + lane*8);
    float4 w1 = *(const float4*)(w + lane*8 + 4);
    float o[8];
    o[0] = v0.x*rs*w0.x; o[1] = v0.y*rs*w0.y; o[2] = v0.z*rs*w0.z; o[3] = v0.w*rs*w0.w;
    o[4] = v1.x*rs*w1.x; o[5] = v1.y*rs*w1.y; o[6] = v1.z*rs*w1.z; o[7] = v1.w*rs*w1.w;

    ushort_t pk[8];
#pragma unroll
    for (int p = 0; p < 8; p++) pk[p] = f2bf(o[p]);
    *(uint4*)(kvnb + (size_t)bs*512 + lane*8) = *(const uint4*)pk;

    if (lane < 32) {
        float xr = row[512 + 2*lane], xi = row[512 + 2*lane + 1];
        float c  = cosT[s*32 + lane], sn = sinT[s*32 + lane];
        ushort_t p2[2] = { f2bf(xr*c - xi*sn), f2bf(xr*sn + xi*c) };
        *(uint_t*)(kpeb + (size_t)bs*64 + 2*lane) = *(const uint_t*)p2;
    }
}

// ---------------------------------------------------------------------------
// stage one 32-key tile: K (36 frag-groups) -> F[buf], V' (8 groups) -> vt[buf]
// lane-linear frag layout; wave w issues its subset.
// ---------------------------------------------------------------------------
__device__ __forceinline__ void stage_tile(const ushort_t* kvn_b, const ushort_t* kpe_b,
                                           const ushort_t* vpT_h, ushort_t* ldsb,
                                           int t0, int buf, int w, int l16, int q8e)
{
    ushort_t* Fb = ldsb + buf*18432;
    ushort_t* Vb = ldsb + 36864 + buf*4096;
#pragma unroll
    for (int ii = 0; ii < 5; ii++) {
        int i = w + ii*8;
        if (i < 36) {
            int g2 = (i >= 18) ? 1 : 0;
            int ks = i - g2*18;
            int row = t0 + g2*16 + l16;
            const ushort_t* src = (ks < 16)
                ? (kvn_b + (size_t)row*512 + ks*32 + q8e)
                : (kpe_b + (size_t)row*64 + (ks-16)*32 + q8e);
            gl_lds16(src, Fb + i*512);
        }
    }
    {
        const ushort_t* src = vpT_h + (size_t)(w*16 + l16)*2048 + t0 + q8e;
        gl_lds16(src, Vb + w*512);
    }
}

// ---------------------------------------------------------------------------
// MFMA flash attention v7: 128 q-rows/block, 8 waves x 16 unique rows, TK=32,
// V'-folded PV (o[8], no epilogue GEMM), double-buffered LDS, 1 barrier/tile.
// ---------------------------------------------------------------------------
__global__ __launch_bounds__(512, 2) void attn_mfma(
    const ushort_t* __restrict__ qb,
    const ushort_t* __restrict__ kvnb,
    const ushort_t* __restrict__ kpeb,
    const ushort_t* __restrict__ vpT,
    const float* __restrict__ cosT,
    const float* __restrict__ sinT,
    const ushort_t* __restrict__ wbkT,
    ushort_t* __restrict__ ovb)
{
    // XCD/LPT swizzle: batch = flat&1, longest causal blocks first
    const int flat = blockIdx.x + 16*blockIdx.y + 256*blockIdx.z;
    const int b    = flat & 1;
    const int rem  = flat >> 1;
    const int h    = rem & 15;
    const int q0   = (15 - (rem >> 4)) << 7;

    const int tid  = threadIdx.x;
    const int w    = tid >> 6;
    const int lane = tid & 63;
    const int l16  = lane & 15;
    const int quad = lane >> 4;
    const int tl   = quad * 4;
    const int lb   = lane & 48;
    const int q8e  = quad * 8;
    const float scale = 0.07216878364870323f;   // 192^-0.5

    // LDS map (ushort elems): F[0]=0, F[1]=18432 (36KB x2); vt[buf]=36864+buf*4096
    // (8KB x2); pt = 45056 + w*640; phase-A scr overlay = 18432 + w*2176 (in F[1])
    __shared__ __align__(16) ushort_t lds[50176];   // 100352 B

    const ushort_t* kvn_b = kvnb + (size_t)b*S_*512;
    const ushort_t* kpe_b = kpeb + (size_t)b*S_*64;
    const ushort_t* vpT_h = vpT + (size_t)(b*16 + h)*128*2048;

    const int r0    = q0 + w*16;
    const int rglob = r0 + l16;

    // ---- prologue: stage tile 0 into buf 0 (hides under phase A)
    stage_tile(kvn_b, kpe_b, vpT_h, lds, 0, 0, w, l16, q8e);

    // ===== phase A: q_abs*scale as B-frags qf[0..15], pe -> qf[16..17]
    ushort_t* paw = lds + 18432 + w*2176;
    const ushort_t* qrow = qb + (size_t)(b*S_ + rglob)*3072 + h*192;
    bf16x8 qa[4], qf[18];
#pragma unroll
    for (int ks = 0; ks < 4; ks++)
        qa[ks] = *(const bf16x8*)(qrow + ks*32 + q8e);

    const ushort_t* wbk_h = wbkT + h*65536;
#pragma unroll
    for (int qq = 0; qq < 4; qq++) {
        f32x4 ab[8];
#pragma unroll
        for (int n = 0; n < 8; n++) ab[n] = (f32x4)(0.f);
#pragma unroll
        for (int n = 0; n < 8; n++) {
            const ushort_t* wp = wbk_h + (qq*128 + n*16 + l16)*128 + q8e;
#pragma unroll
            for (int ks = 0; ks < 4; ks++) {
                bf16x8 bw = *(const bf16x8*)(wp + ks*32);
                ab[n] = __builtin_amdgcn_mfma_f32_16x16x32_bf16(qa[ks], bw, ab[n], 0, 0, 0);
            }
        }
        asm volatile("" ::: "memory");
#pragma unroll
        for (int n = 0; n < 8; n++)
#pragma unroll
            for (int r = 0; r < 4; r++)
                paw[(tl + r)*136 + n*16 + l16] = f2bf(ab[n][r] * scale);
        asm volatile("" ::: "memory");
#pragma unroll
        for (int ks2 = 0; ks2 < 4; ks2++)
            qf[qq*4 + ks2] = *(const bf16x8*)(paw + l16*136 + ks2*32 + q8e);
        asm volatile("" ::: "memory");
    }

#pragma unroll
    for (int kk = 0; kk < 2; kk++) {
        int off = kk*32 + q8e;
        uint4 pv4 = *(const uint4*)(qrow + 128 + off);
        const ushort_t* pe = (const ushort_t*)&pv4;
        ushort_t pk[8];
#pragma unroll
        for (int u2 = 0; u2 < 4; u2++) {
            float xr = bf2f(pe[2*u2]), xi = bf2f(pe[2*u2+1]);
            int pi = (off >> 1) + u2;
            float c = cosT[rglob*32 + pi], sn = sinT[rglob*32 + pi];
            pk[2*u2]   = f2bf((xr*c  - xi*sn) * scale);
            pk[2*u2+1] = f2bf((xr*sn + xi*c ) * scale);
        }
        qf[16 + kk] = *(const bf16x8*)pk;
    }
    __syncthreads();   // phase-A LDS done + tile0 staging drained

    // ===== flash main loop: TK=32, double-buffered, 1 barrier/tile =====
    f32x4 o[8];
#pragma unroll
    for (int n = 0; n < 8; n++) o[n] = (f32x4)(0.f);
    float m_s = -1e30f, l_s = 0.f;

    const int bniter = (q0 >> 5) + 4;            // block-uniform tile count
    const int wniter = ((r0 + 15) >> 5) + 1;     // this wave's causal bound
    ushort_t* ptw = lds + 45056 + w*640;
    int cur = 0;

#pragma unroll 1
    for (int it = 0; it < bniter; it++) {
        if (it + 1 < bniter)
            stage_tile(kvn_b, kpe_b, vpT_h, lds, (it+1)*32, cur ^ 1, w, l16, q8e);

        if (it < wniter) {
            const int t0 = it * 32;
            const ushort_t* Fb = lds + cur*18432;
            const ushort_t* Vb = lds + 36864 + cur*4096;

            // S^T: C col = q-row (l16), C row = key (tl+reg); two 16-key groups
            f32x4 s0 = (f32x4)(0.f), s1 = (f32x4)(0.f);
#pragma unroll
            for (int ks = 0; ks < 18; ks++) {
                bf16x8 kf0 = *(const bf16x8*)(Fb + ks*512 + lane*8);
                s0 = __builtin_amdgcn_mfma_f32_16x16x32_bf16(kf0, qf[ks], s0, 0, 0, 0);
                bf16x8 kf1 = *(const bf16x8*)(Fb + 9216 + ks*512 + lane*8);
                s1 = __builtin_amdgcn_mfma_f32_16x16x32_bf16(kf1, qf[ks], s1, 0, 0, 0);
            }

            // online softmax for q-row rglob
            float pv[8];
            float mx = -1e30f;
#pragma unroll
            for (int reg = 0; reg < 4; reg++) {
                pv[reg]   = ((t0 + tl + reg)      <= rglob) ? s0[reg] : -1e30f;
                pv[4+reg] = ((t0 + 16 + tl + reg) <= rglob) ? s1[reg] : -1e30f;
                mx = fmaxf(mx, fmaxf(pv[reg], pv[4+reg]));
            }
            mx = fmaxf(mx, __shfl_xor(mx, 16));
            mx = fmaxf(mx, __shfl_xor(mx, 32));
            if (!__all(mx <= m_s)) {        // exact skip when max unchanged
                float mn = fmaxf(m_s, mx);
                float al = __expf(m_s - mn);
                m_s = mn;
                l_s *= al;
                f32x4 alv;
#pragma unroll
                for (int reg = 0; reg < 4; reg++) alv[reg] = __shfl(al, lb + tl + reg, 64);
#pragma unroll
                for (int n = 0; n < 8; n++) o[n] *= alv;
            }
            float ps = 0.f;
#pragma unroll
            for (int reg = 0; reg < 8; reg++) {
                pv[reg] = (pv[reg] > -1e29f) ? __expf(pv[reg] - m_s) : 0.f;
                ps += pv[reg];
            }
            ps += __shfl_xor(ps, 16);
            ps += __shfl_xor(ps, 32);
            l_s += ps;

            // P^T -> ptw (per-wave), fence, read back A-frag (k=32)
            ushort_t pk4[8];
#pragma unroll
            for (int reg = 0; reg < 8; reg++) pk4[reg] = f2bf(pv[reg]);
            *(uint2*)(ptw + l16*40 + tl)      = *(const uint2*)(pk4);
            *(uint2*)(ptw + l16*40 + 16 + tl) = *(const uint2*)(pk4 + 4);
            asm volatile("" ::: "memory");
            bf16x8 ap = *(const bf16x8*)(ptw + l16*40 + q8e);
            asm volatile("" ::: "memory");

            // PV': o[n] += P[r][t] * V'[t][c], c = n*16 + l16 (128-dim output)
#pragma unroll
            for (int n = 0; n < 8; n++) {
                bf16x8 bv = *(const bf16x8*)(Vb + n*512 + lane*8);
                o[n] = __builtin_amdgcn_mfma_f32_16x16x32_bf16(ap, bv, o[n], 0, 0, 0);
            }
        }
        __syncthreads();   // next-tile staging drained + cur-buffer reads done
        cur ^= 1;
    }

    // ===== output: ovb = o / l (no epilogue GEMM) =====
    float linv = 1.f / l_s;
    f32x4 rlv;
#pragma unroll
    for (int reg = 0; reg < 4; reg++) rlv[reg] = __shfl(linv, lb + tl + reg, 64);

    ushort_t* orow = ovb + (size_t)(b*S_ + r0)*2048 + h*128;
#pragma unroll
    for (int n = 0; n < 8; n++)
#pragma unroll
        for (int reg = 0; reg < 4; reg++)
            orow[(size_t)(tl + reg)*2048 + n*16 + l16] = f2bf(o[n][reg] * rlv[reg]);
}

// ---------------------------------------------------------------------------
extern "C" void kernel_launch(void* const* d_in, const int* in_sizes, int n_in,
                              void* d_out, int out_size, void* d_ws, size_t ws_size,
                              hipStream_t stream) {
    const float* x     = (const float*)d_in[0];
    const float* cosT  = (const float*)d_in[1];
    const float* sinT  = (const float*)d_in[2];
    // d_in[3] mask: unused (causality applied directly)
    const float* wq    = (const float*)d_in[4];
    const float* wkv_a = (const float*)d_in[5];
    const float* kvw   = (const float*)d_in[6];
    const float* wkv_b = (const float*)d_in[7];
    const float* wo    = (const float*)d_in[8];
    float* out = (float*)d_out;

    ushort_t* qb   = (ushort_t*)d_ws;       // 4096x3072 bf16
    ushort_t* xb   = qb   + 12582912;       // 4096x2048 (dead after q-proj; reused as vpT)
    ushort_t* wqb  = xb   + 8388608;        // 3072x2048
    ushort_t* wob  = wqb  + 6291456;        // 2048x2048
    ushort_t* ovb  = wob  + 4194304;        // 4096x2048
    ushort_t* kvnb = ovb  + 8388608;        // 4096x512
    ushort_t* kpeb = kvnb + 2097152;        // 4096x64
    ushort_t* kvnT = kpeb + 262144;         // (unused slot, 2x512x2048)
    ushort_t* wbkT = kvnT + 2097152;        // 16x512x128
    ushort_t* wbvB = wbkT + 1048576;        // 16x128x512
    float*    kvr  = (float*)(wbvB + 1048576);  // 4096x576 f32
    ushort_t* vpT  = xb;                    // 2x16x128x2048 bf16 (aliases xb)

    dim3 blk(256);
    cast_bf16<<<dim3(8192), blk, 0, stream>>>(x,  xb,  8388608);
    cast_bf16<<<dim3(6144), blk, 0, stream>>>(wq, wqb, 6291456);
    cast_bf16<<<dim3(4096), blk, 0, stream>>>(wo, wob, 4194304);
    prep_wb<<<dim3(4096), blk, 0, stream>>>(wkv_b, wbkT, wbvB);
    gemm_bf16<<<dim3(3072/128, 4096/128), blk, 0, stream>>>(xb, wqb, nullptr, qb, 4096, 3072, 2048, 1);
    gemm_nt<<<dim3(576/64, 4096/64), blk, 0, stream>>>(x, wkv_a, kvr, 4096, 576, 2048, 2048, 2048, 576);
    kv_norm_rope<<<dim3(4096/4), blk, 0, stream>>>(kvr, kvw, cosT, sinT, kvnb, kpeb);
    gemm_vp<<<dim3(4096/128, 16), blk, 0, stream>>>(kvnb, wbvB, vpT);
    attn_mfma<<<dim3(S_/128, H_, B_), dim3(512), 0, stream>>>(qb, kvnb, kpeb, vpT, cosT, sinT, wbkT, ovb);
    gemm_bf16<<<dim3(2048/128, 4096/128), blk, 0, stream>>>(ovb, wob, out, nullptr, 4096, 2048, 2048, 0);
}